// Round 4
// baseline (25.562 us; speedup 1.0000x reference)
//
#include <hip/hip_runtime.h>

// Reference collapses: softmax over a singleton axis == 1.0 exactly, so
// a = attn(Q,K)+attn(Q,T)+attn(T,K) = 3.0 everywhere and out = 3.0 * x.
// Pure streaming elementwise scale: 64 MiB in + 64 MiB out.
//
// 4194304 float4 = 2048 blocks * 256 threads * 8 float4/thread exactly.
// Each block owns 32 KiB contiguous; all 8 loads issued before any store
// (8 outstanding global_load_dwordx4 per lane for max MLP). No nt hints
// (round-2: nt + far stride regressed; round-3 contiguous plain = best).

typedef float f4 __attribute__((ext_vector_type(4)));

__global__ void __launch_bounds__(256) esra_scale3_kernel(
    const f4* __restrict__ x, f4* __restrict__ out) {
    const int base = blockIdx.x * 2048 + threadIdx.x;

    f4 v0 = x[base];
    f4 v1 = x[base + 256];
    f4 v2 = x[base + 512];
    f4 v3 = x[base + 768];
    f4 v4 = x[base + 1024];
    f4 v5 = x[base + 1280];
    f4 v6 = x[base + 1536];
    f4 v7 = x[base + 1792];

    v0 *= 3.0f; v1 *= 3.0f; v2 *= 3.0f; v3 *= 3.0f;
    v4 *= 3.0f; v5 *= 3.0f; v6 *= 3.0f; v7 *= 3.0f;

    out[base]        = v0;
    out[base + 256]  = v1;
    out[base + 512]  = v2;
    out[base + 768]  = v3;
    out[base + 1024] = v4;
    out[base + 1280] = v5;
    out[base + 1536] = v6;
    out[base + 1792] = v7;
}

extern "C" void kernel_launch(void* const* d_in, const int* in_sizes, int n_in,
                              void* d_out, int out_size, void* d_ws, size_t ws_size,
                              hipStream_t stream) {
    const f4* x = (const f4*)d_in[0];   // [B,C,H,W] fp32, 16*256*64*64
    f4* out = (f4*)d_out;
    // out_size == 16777216 floats; 4194304 float4 == 2048 * 256 * 8 exactly.
    const int block = 256;
    const int grid = 2048;
    esra_scale3_kernel<<<grid, block, 0, stream>>>(x, out);
}

// Round 5
// 24.892 us; speedup vs baseline: 1.0269x; 1.0269x over previous
//
#include <hip/hip_runtime.h>

// Reference collapses: softmax over a singleton axis == 1.0 exactly, so
// a = attn(Q,K)+attn(Q,T)+attn(T,K) = 3.0 everywhere and out = 3.0 * x.
// Pure streaming elementwise scale: 64 MiB in + 64 MiB out.
//
// Final form (best of rounds 1-4 sweep): 4096 blocks * 256 threads *
// 4 float4/thread, block-contiguous 16 KiB regions, plain loads/stores.
// A/B history: grid-stride 2048 = 25.6 us; nt + 16MiB-stride = 28.2 us;
// this = 24.8 us; 8 f4/thread = 25.6 us. 24.8 us = 5.4 TB/s on 134 MB
// mandatory traffic ~= copy roofline + ~3 us launch/ramp overhead.

typedef float f4 __attribute__((ext_vector_type(4)));

__global__ void __launch_bounds__(256) esra_scale3_kernel(
    const f4* __restrict__ x, f4* __restrict__ out) {
    const int base = blockIdx.x * 1024 + threadIdx.x;

    f4 v0 = x[base];
    f4 v1 = x[base + 256];
    f4 v2 = x[base + 512];
    f4 v3 = x[base + 768];

    v0 *= 3.0f;
    v1 *= 3.0f;
    v2 *= 3.0f;
    v3 *= 3.0f;

    out[base]       = v0;
    out[base + 256] = v1;
    out[base + 512] = v2;
    out[base + 768] = v3;
}

extern "C" void kernel_launch(void* const* d_in, const int* in_sizes, int n_in,
                              void* d_out, int out_size, void* d_ws, size_t ws_size,
                              hipStream_t stream) {
    const f4* x = (const f4*)d_in[0];   // [B,C,H,W] fp32, 16*256*64*64
    f4* out = (f4*)d_out;
    // out_size == 16777216 floats; 4194304 float4 == 4096 * 256 * 4 exactly.
    const int block = 256;
    const int grid = 4096;
    esra_scale3_kernel<<<grid, block, 0, stream>>>(x, out);
}